// Round 2
// baseline (2059.135 us; speedup 1.0000x reference)
//
#include <hip/hip_runtime.h>
#include <cstdint>
#include <cstddef>

#define B_  2
#define C_  256
#define NH_ 8
#define LV_ 4
#define P_  4
#define L_  6
#define F_  1024
#define N_  21760
#define M_  (B_*N_)   // 43520

typedef unsigned short ushort_t;
typedef __attribute__((ext_vector_type(8))) short bf16x8;
typedef __attribute__((ext_vector_type(4))) float f32x4;
typedef __attribute__((ext_vector_type(2))) float f32x2;

__device__ __forceinline__ float b2f(ushort_t u){
    union { unsigned int i; float f; } v; v.i = ((unsigned int)u) << 16; return v.f;
}
__device__ __forceinline__ ushort_t f2b(float f){
    union { float f; unsigned int i; } v; v.f = f;
    return (ushort_t)((v.i + 0x7fffu + ((v.i >> 16) & 1u)) >> 16);
}

// async global->LDS, 16B per lane, dst = wave-uniform base + lane*16
__device__ __forceinline__ void gload16(const void* g, void* l){
    __builtin_amdgcn_global_load_lds(
        (const __attribute__((address_space(1))) unsigned int*)g,
        (__attribute__((address_space(3))) unsigned int*)l, 16, 0, 0);
}

// ---------------------------------------------------------------------------
// Coalesced concat+transpose init. Block = one 32x32 tile of one (b,level).
// ---------------------------------------------------------------------------
__global__ __launch_bounds__(256) void concat_init_kernel(
    const float* __restrict__ s0, const float* __restrict__ s1,
    const float* __restrict__ s2, const float* __restrict__ s3,
    const float* __restrict__ p0, const float* __restrict__ p1,
    const float* __restrict__ p2, const float* __restrict__ p3,
    const float* __restrict__ le, float* __restrict__ X,
    ushort_t* __restrict__ POSB, ushort_t* __restrict__ XB,
    ushort_t* __restrict__ QB)
{
    int bid = blockIdx.x;
    int b = bid / 5440;
    int r = bid - b * 5440;
    const float* sp; const float* pp; int li, st, hw, t;
    if      (r < 4096){ li=0; st=0;     hw=16384; t=r;        sp=s0; pp=p0; }
    else if (r < 5120){ li=1; st=16384; hw=4096;  t=r-4096;   sp=s1; pp=p1; }
    else if (r < 5376){ li=2; st=20480; hw=1024;  t=r-5120;   sp=s2; pp=p2; }
    else              { li=3; st=21504; hw=256;   t=r-5376;   sp=s3; pp=p3; }
    int pt = t >> 3, ct = t & 7;   // pix-tile, c-tile (C/32 = 8)

    __shared__ float ts[32][33], tp[32][33];
    int tx  = threadIdx.x & 31;
    int ty8 = threadIdx.x >> 5;    // 0..7
#pragma unroll
    for (int i = 0; i < 4; i++) {
        int c   = ct * 32 + ty8 + i * 8;
        int pix = pt * 32 + tx;
        size_t so = ((size_t)b * C_ + c) * hw + pix;
        ts[ty8 + i * 8][tx] = sp[so];
        tp[ty8 + i * 8][tx] = pp[so];
    }
    __syncthreads();
#pragma unroll
    for (int i = 0; i < 4; i++) {
        int cw = tx, pw = ty8 + i * 8;
        int c = ct * 32 + cw;
        int n = st + pt * 32 + pw;
        size_t o = ((size_t)b * N_ + n) * C_ + c;
        float xv = ts[cw][pw];
        float pv = tp[cw][pw] + le[li * C_ + c];
        X[o]    = xv;
        XB[o]   = f2b(xv);
        POSB[o] = f2b(pv);
        QB[o]   = f2b(xv + pv);
    }
}

// ---------------------------------------------------------------------------
// Weight prep: fp32 [L][K][N] -> bf16 [l*outStride + n*K + k]  (transpose+cast)
// ---------------------------------------------------------------------------
__global__ __launch_bounds__(256) void wprep_kernel(
    const float* __restrict__ in, ushort_t* __restrict__ out,
    int K, int Nn, long outLayerStride)
{
    int idx = blockIdx.x * 256 + threadIdx.x;     // < L*K*N
    int per = K * Nn;
    int l   = idx / per;
    int rem = idx - l * per;
    int k   = rem / Nn;
    int nn  = rem - k * Nn;
    out[(long)l * outLayerStride + (long)nn * K + k] = f2b(in[idx]);
}

// packed bias for fused off+att GEMM: pb[l][0:256]=boff, [256:384]=batt
__global__ __launch_bounds__(256) void bias_pack_kernel(
    const float* __restrict__ boff, const float* __restrict__ batt,
    float* __restrict__ pb)
{
    int i = blockIdx.x * 256 + threadIdx.x;       // < 6*384
    if (i >= 6 * 384) return;
    int l = i / 384, j = i - l * 384;
    pb[i] = (j < 256) ? boff[l * 256 + j] : batt[l * 128 + j - 256];
}

// ---------------------------------------------------------------------------
// bf16 MFMA GEMM: C[M,N] = A[M,K](bf16) @ BT[N,K](bf16)^T + bias (fp32)
// 128x128 tile, BK=64 staged as two 32-halves, 256 thr = 4 waves (2x2 of
// 64x64), 16x16x32 MFMA. Used for val, off+att, ff1 (LN-free outputs).
// ---------------------------------------------------------------------------
__global__ __launch_bounds__(256) void gemm_bf16_kernel(
    const ushort_t* __restrict__ A, const ushort_t* __restrict__ BT,
    const float* __restrict__ bias,
    ushort_t* __restrict__ Cb, float* __restrict__ Cf, float* __restrict__ Cf2,
    int M, int Nn, int K, int Nsplit, int relu)
{
    __shared__ ushort_t Alds[2][128*32];
    __shared__ ushort_t Blds[2][128*32];
    const int tid  = threadIdx.x;
    const int wave = tid >> 6, lane = tid & 63;
    const int bm = blockIdx.y * 128, bn = blockIdx.x * 128;
    const int wm = (wave >> 1) * 64, wn = (wave & 1) * 64;

    const int c0 = wave * 2, c1 = wave * 2 + 1;
    const int rIn = lane >> 2;
    const int cIn = (lane & 3) * 8;
    const ushort_t* Ag0 = A  + (size_t)(bm + c0*16 + rIn) * K + cIn;
    const ushort_t* Ag1 = A  + (size_t)(bm + c1*16 + rIn) * K + cIn;
    const ushort_t* Bg0 = BT + (size_t)(bn + c0*16 + rIn) * K + cIn;
    const ushort_t* Bg1 = BT + (size_t)(bn + c1*16 + rIn) * K + cIn;

    const int fm    = lane & 15;
    const int quad8 = (lane >> 4) * 8;

    f32x4 acc[4][4];
#pragma unroll
    for (int i = 0; i < 4; i++)
#pragma unroll
        for (int j = 0; j < 4; j++) acc[i][j] = (f32x4){0.f,0.f,0.f,0.f};

    for (int k0 = 0; k0 < K; k0 += 64) {
        gload16(Ag0 + k0,      &Alds[0][c0*512]);
        gload16(Ag1 + k0,      &Alds[0][c1*512]);
        gload16(Bg0 + k0,      &Blds[0][c0*512]);
        gload16(Bg1 + k0,      &Blds[0][c1*512]);
        gload16(Ag0 + k0 + 32, &Alds[1][c0*512]);
        gload16(Ag1 + k0 + 32, &Alds[1][c1*512]);
        gload16(Bg0 + k0 + 32, &Blds[1][c0*512]);
        gload16(Bg1 + k0 + 32, &Blds[1][c1*512]);
        __syncthreads();
#pragma unroll
        for (int h = 0; h < 2; h++) {
            bf16x8 af[4], bfr[4];
#pragma unroll
            for (int i = 0; i < 4; i++)
                af[i]  = *(const bf16x8*)&Alds[h][(wm + i*16 + fm) * 32 + quad8];
#pragma unroll
            for (int j = 0; j < 4; j++)
                bfr[j] = *(const bf16x8*)&Blds[h][(wn + j*16 + fm) * 32 + quad8];
#pragma unroll
            for (int i = 0; i < 4; i++)
#pragma unroll
                for (int j = 0; j < 4; j++)
                    acc[i][j] = __builtin_amdgcn_mfma_f32_16x16x32_bf16(af[i], bfr[j], acc[i][j], 0, 0, 0);
        }
        __syncthreads();
    }

    const int rq = (lane >> 4) * 4;
#pragma unroll
    for (int j = 0; j < 4; j++) {
        int col = bn + wn + j*16 + fm;
        float bb = bias[col];
#pragma unroll
        for (int i = 0; i < 4; i++) {
            int row0 = bm + wm + i*16 + rq;
#pragma unroll
            for (int r = 0; r < 4; r++) {
                float v = acc[i][j][r] + bb;
                if (relu) v = fmaxf(v, 0.f);
                if (Cb) {
                    Cb[(size_t)(row0 + r) * Nn + col] = f2b(v);
                } else if (col < Nsplit) {
                    Cf[(size_t)(row0 + r) * Nsplit + col] = v;
                } else {
                    Cf2[(size_t)(row0 + r) * (Nn - Nsplit) + (col - Nsplit)] = v;
                }
            }
        }
    }
}

// ---------------------------------------------------------------------------
// Fused GEMM + residual + LayerNorm.  C = A[M,K] @ BT[256,K]^T + bias;
// x = LN(X + C)*g + beta; writes X (fp32), XB (bf16), optional QB=bf16(x+POSB).
// BM=64, BN=256 (full row in one block -> LN per-row possible).
// 256 thr = 4 waves (1x4 of 64x64), grid = M/64 = 680 blocks.
// LDS: staging S = 2*(64+256)*32*2B = 40KB exactly -> 4 blocks/CU.
// LN partials overlay S after the final K-loop barrier.
// Residual is added in fp32 (closer to reference than the old bf16 VALB path).
// ---------------------------------------------------------------------------
__global__ __launch_bounds__(256) void gemm_ln_kernel(
    const ushort_t* __restrict__ A, const ushort_t* __restrict__ BT,
    const float* __restrict__ bias, int K,
    float* __restrict__ X, ushort_t* __restrict__ XB,
    const float* __restrict__ g, const float* __restrict__ beta,
    const ushort_t* __restrict__ POSBp, ushort_t* __restrict__ QBp)
{
    __shared__ ushort_t S[2][320*32];   // [half][A rows 0..63 | B rows 0..255]
    const int tid  = threadIdx.x;
    const int wave = tid >> 6, lane = tid & 63;
    const int bm = blockIdx.x * 64;
    const int wn = wave * 64;

    // staging: 20 units of 16 rows x 32 cols (1KB); wave w stages units 5w..5w+4
    const int rIn = lane >> 2;
    const int cIn = (lane & 3) * 8;
    const ushort_t* gp[5];
    int ldst[5];
#pragma unroll
    for (int uu = 0; uu < 5; uu++) {
        int u = wave * 5 + uu;
        ldst[uu] = u * 512;             // A units 0..3 -> 0..2047; B 4..19 -> 2048..10239
        gp[uu] = (u < 4) ? A  + (size_t)(bm + u*16 + rIn) * K + cIn
                         : BT + (size_t)((u - 4)*16 + rIn) * K + cIn;
    }

    const int fm    = lane & 15;
    const int quad8 = (lane >> 4) * 8;

    f32x4 acc[4][4];
#pragma unroll
    for (int i = 0; i < 4; i++)
#pragma unroll
        for (int j = 0; j < 4; j++) acc[i][j] = (f32x4){0.f,0.f,0.f,0.f};

    for (int k0 = 0; k0 < K; k0 += 64) {
#pragma unroll
        for (int uu = 0; uu < 5; uu++) {
            gload16(gp[uu] + k0,      &S[0][ldst[uu]]);
            gload16(gp[uu] + k0 + 32, &S[1][ldst[uu]]);
        }
        __syncthreads();
#pragma unroll
        for (int h = 0; h < 2; h++) {
            bf16x8 af[4], bfr[4];
#pragma unroll
            for (int i = 0; i < 4; i++)
                af[i]  = *(const bf16x8*)&S[h][(i*16 + fm) * 32 + quad8];
#pragma unroll
            for (int j = 0; j < 4; j++)
                bfr[j] = *(const bf16x8*)&S[h][2048 + (wn + j*16 + fm) * 32 + quad8];
#pragma unroll
            for (int i = 0; i < 4; i++)
#pragma unroll
                for (int j = 0; j < 4; j++)
                    acc[i][j] = __builtin_amdgcn_mfma_f32_16x16x32_bf16(af[i], bfr[j], acc[i][j], 0, 0, 0);
        }
        __syncthreads();
    }

    // ---- epilogue: bias + fp32 residual, then LN ----
    // LDS reuse (safe after the trailing barrier): partials + stats
    float2* part = (float2*)&S[0][0];      // [4 colgroups][64 rows]
    float2* stat = (float2*)&S[0][2048];   // [64 rows] = (mu, rs)

    float bb[4], gg[4], be[4];
#pragma unroll
    for (int j = 0; j < 4; j++) {
        int col = wn + j*16 + fm;
        bb[j] = bias[col]; gg[j] = g[col]; be[j] = beta[col];
    }

    const int rq = (lane >> 4) * 4;
#pragma unroll
    for (int i = 0; i < 4; i++)
#pragma unroll
        for (int r = 0; r < 4; r++) {
            const float* xr = X + (size_t)(bm + i*16 + rq + r) * 256 + wn + fm;
#pragma unroll
            for (int j = 0; j < 4; j++)
                acc[i][j][r] += bb[j] + xr[j*16];
        }

    // per-row (s, s2): sum 4 cols locally, reduce over the 16 fm lanes
#pragma unroll
    for (int i = 0; i < 4; i++)
#pragma unroll
        for (int r = 0; r < 4; r++) {
            float v0 = acc[i][0][r], v1 = acc[i][1][r], v2 = acc[i][2][r], v3 = acc[i][3][r];
            float s  = v0 + v1 + v2 + v3;
            float s2 = v0*v0 + v1*v1 + v2*v2 + v3*v3;
#pragma unroll
            for (int m = 1; m < 16; m <<= 1) {
                s  += __shfl_xor(s,  m, 64);
                s2 += __shfl_xor(s2, m, 64);
            }
            if (fm == 0) part[wave * 64 + i*16 + rq + r] = (float2){s, s2};
        }
    __syncthreads();
    if (tid < 64) {
        float s = 0.f, s2 = 0.f;
#pragma unroll
        for (int cg = 0; cg < 4; cg++) {
            float2 p = part[cg * 64 + tid];
            s += p.x; s2 += p.y;
        }
        float mu  = s * (1.f / C_);
        float var = s2 * (1.f / C_) - mu * mu;
        stat[tid] = (float2){mu, rsqrtf(var + 1e-5f)};
    }
    __syncthreads();

#pragma unroll
    for (int i = 0; i < 4; i++)
#pragma unroll
        for (int r = 0; r < 4; r++) {
            int il = i*16 + rq + r;
            float2 st = stat[il];
            size_t rb = (size_t)(bm + il) * 256 + wn + fm;
#pragma unroll
            for (int j = 0; j < 4; j++) {
                float o = (acc[i][j][r] - st.x) * st.y * gg[j] + be[j];
                X[rb + j*16]  = o;
                XB[rb + j*16] = f2b(o);
                if (QBp) QBp[rb + j*16] = f2b(o + b2f(POSBp[rb + j*16]));
            }
        }
}

// ---------------------------------------------------------------------------
// Deformable sampling, 2-phase. Block = 128 thr per FOUR queries.
// ---------------------------------------------------------------------------
__global__ __launch_bounds__(128) void msdeform_kernel(
    const ushort_t* __restrict__ VALb, const float* __restrict__ OFF,
    const float* __restrict__ ATT, ushort_t* __restrict__ SAMPb)
{
    const int bq0 = blockIdx.x << 2;          // first of 4 query indices
    const int b   = bq0 / N_;                 // block-uniform (N_ % 4 == 0)
    const int tid = threadIdx.x;

    __shared__ int2 s_wi[32 * 65];            // [G = qi*8+head][64 +1 pad]

    {   // phase 1 — head = tid>>4, li = (tid>>2)&3, p = tid&3
        const int head = tid >> 4, li = (tid >> 2) & 3;
        const int HS[4] = {128, 64, 32, 16};
        const int ST[4] = {0, 16384, 20480, 21504};
        const int wl = HS[li], stl = ST[li];
        const float fw = (float)wl;

#pragma unroll
        for (int qi = 0; qi < 4; qi++) {
            const int bn = bq0 + qi;
            const int n  = bn - b * N_;
            float logit = ATT[(size_t)bn * 128 + tid];
            float2 o2 = *(const float2*)(OFF + (size_t)bn * 256 + tid * 2);
            float ox = o2.x, oy = o2.y;
            float mx = logit;
#pragma unroll
            for (int s = 1; s < 16; s <<= 1) mx = fmaxf(mx, __shfl_xor(mx, s, 16));
            float e = __expf(logit - mx), sm = e;
#pragma unroll
            for (int s = 1; s < 16; s <<= 1) sm += __shfl_xor(sm, s, 16);
            float aw = e / sm;

            int sq, lwq;
            if      (n < 16384){ sq = 0;     lwq = 7; }
            else if (n < 20480){ sq = 16384; lwq = 6; }
            else if (n < 21504){ sq = 20480; lwq = 5; }
            else               { sq = 21504; lwq = 4; }
            int pidx = n - sq;
            int prow = pidx >> lwq, pcol = pidx & ((1 << lwq) - 1);
            float inv = 1.f / (float)(1 << lwq);
            float refx = (pcol + 0.5f) * inv;
            float refy = (prow + 0.5f) * inv;

            float xx = refx * fw + ox - 0.5f;   // (refx + ox/w)*w - 0.5
            float yy = refy * fw + oy - 0.5f;
            float xf = floorf(xx), yf = floorf(yy);
            float wx = xx - xf, wy = yy - yf;
            int x0 = (int)xf, y0 = (int)yf;
            const int base = (qi * 8 + head) * 65 + (tid & 15) * 4;
#pragma unroll
            for (int c2 = 0; c2 < 4; c2++) {
                int dx = c2 & 1, dy = c2 >> 1;
                int xi = x0 + dx, yi = y0 + dy;
                float wgt = (dx ? wx : 1.f - wx) * (dy ? wy : 1.f - wy);
                bool valid = (xi >= 0) & (xi < wl) & (yi >= 0) & (yi < wl);
                int xc = min(max(xi, 0), wl - 1), yc = min(max(yi, 0), wl - 1);
                int2 wi;
                wi.x = ((stl + yc * wl + xc) * C_ + head * 32) * 2;  // byte off
                wi.y = __float_as_int(valid ? aw * wgt : 0.f);
                s_wi[base + c2] = wi;
            }
        }
    }
    __syncthreads();

    // phase 2 — q2 = tid>>5, head = (tid>>2)&7, 16B chunk = tid&3
    const int q2     = tid >> 5;
    const int within = tid & 31;
    const int head   = within >> 2;
    const int ch16   = (within & 3) << 4;     // byte offset inside head's 64B
    const int bn     = bq0 + q2;
    const char* vb   = (const char*)(VALb + (size_t)b * (N_ * C_)); // SGPR base
    const int sbase  = (q2 * 8 + head) * 65;

    f32x2 a0 = {0.f,0.f}, a1 = {0.f,0.f}, a2 = {0.f,0.f}, a3 = {0.f,0.f};
#pragma unroll 8
    for (int j = 0; j < 64; j++) {
        int2 wi = s_wi[sbase + j];
        float w = __int_as_float(wi.y);
        f32x2 w2 = {w, w};
        uint4 u = *(const uint4*)(vb + (unsigned)(wi.x + ch16));
        f32x2 f;
        f.x = __uint_as_float(u.x << 16);
        f.y = __uint_as_float(u.x & 0xffff0000u);
        a0 += w2 * f;
        f.x = __uint_as_float(u.y << 16);
        f.y = __uint_as_float(u.y & 0xffff0000u);
        a1 += w2 * f;
        f.x = __uint_as_float(u.z << 16);
        f.y = __uint_as_float(u.z & 0xffff0000u);
        a2 += w2 * f;
        f.x = __uint_as_float(u.w << 16);
        f.y = __uint_as_float(u.w & 0xffff0000u);
        a3 += w2 * f;
    }
    uint4 o;
    o.x = (unsigned)f2b(a0.x) | ((unsigned)f2b(a0.y) << 16);
    o.y = (unsigned)f2b(a1.x) | ((unsigned)f2b(a1.y) << 16);
    o.z = (unsigned)f2b(a2.x) | ((unsigned)f2b(a2.y) << 16);
    o.w = (unsigned)f2b(a3.x) | ((unsigned)f2b(a3.y) << 16);
    *(uint4*)(SAMPb + (size_t)bn * C_ + head * 32 + ((within & 3) << 3)) = o;
}

// ---------------------------------------------------------------------------
// Workspace (bytes), ~185.3 MB:
//   POSB bf16 22.28M | OFFf f32 44.56M | ATTf f32 22.28M | SAMPB bf16 22.28M |
//   VALB bf16 22.28M | XB 22.28M | QB 22.28M | WT bf16 9.04M | PB 9216B
//   FFN hidden HB (bf16, M*1024) overlays [OFFf|ATTf|SAMPB] exactly.
//   VALB now only feeds msdeform (out/ffn outputs go straight through LN).
// ---------------------------------------------------------------------------
extern "C" void kernel_launch(void* const* d_in, const int* in_sizes, int n_in,
                              void* d_out, int out_size, void* d_ws, size_t ws_size,
                              hipStream_t stream)
{
    const float *srcs[4], *poss[4];
    if (in_sizes[1] == in_sizes[0]) {   // interleaved src0,pos0,src1,pos1,...
        srcs[0] = (const float*)d_in[0]; poss[0] = (const float*)d_in[1];
        srcs[1] = (const float*)d_in[2]; poss[1] = (const float*)d_in[3];
        srcs[2] = (const float*)d_in[4]; poss[2] = (const float*)d_in[5];
        srcs[3] = (const float*)d_in[6]; poss[3] = (const float*)d_in[7];
    } else {
        srcs[0] = (const float*)d_in[0]; srcs[1] = (const float*)d_in[1];
        srcs[2] = (const float*)d_in[2]; srcs[3] = (const float*)d_in[3];
        poss[0] = (const float*)d_in[4]; poss[1] = (const float*)d_in[5];
        poss[2] = (const float*)d_in[6]; poss[3] = (const float*)d_in[7];
    }
    const float* le = (const float*)d_in[8];

    float* X = (float*)d_out;
    char* w = (char*)d_ws;
    ushort_t* POSB  = (ushort_t*)w;           w += (size_t)M_ * C_ * 2;
    float*    OFFf  = (float*)w;              w += (size_t)M_ * C_ * 4;
    float*    ATTf  = (float*)w;              w += (size_t)M_ * 128 * 4;
    ushort_t* SAMPB = (ushort_t*)w;           w += (size_t)M_ * C_ * 2;
    ushort_t* VALB  = (ushort_t*)w;           w += (size_t)M_ * C_ * 2;
    ushort_t* XB    = (ushort_t*)w;           w += (size_t)M_ * C_ * 2;
    ushort_t* QB    = (ushort_t*)w;           w += (size_t)M_ * C_ * 2;
    ushort_t* WT    = (ushort_t*)w;           w += (size_t)6 * 753664 * 2;
    float*    PB    = (float*)w;
    ushort_t* HB    = (ushort_t*)OFFf;        // overlays OFFf|ATTf|SAMPB exactly

    // per-layer WT element offsets ([val][off|att packed][out][ff1][ff2])
    const long LSTRIDE = 753664;
    const long O_WVAL = 0, O_WOFF = 65536, O_WATT = 131072, O_WOUT = 163840,
               O_WF1 = 229376, O_WF2 = 491520;

    wprep_kernel<<<6*65536/256, 256, 0, stream>>>((const float*)d_in[13], WT + O_WVAL, 256, 256,  LSTRIDE);
    wprep_kernel<<<6*65536/256, 256, 0, stream>>>((const float*)d_in[9],  WT + O_WOFF, 256, 256,  LSTRIDE);
    wprep_kernel<<<6*32768/256, 256, 0, stream>>>((const float*)d_in[11], WT + O_WATT, 256, 128,  LSTRIDE);
    wprep_kernel<<<6*65536/256, 256, 0, stream>>>((const float*)d_in[15], WT + O_WOUT, 256, 256,  LSTRIDE);
    wprep_kernel<<<6*262144/256,256, 0, stream>>>((const float*)d_in[19], WT + O_WF1,  256, 1024, LSTRIDE);
    wprep_kernel<<<6*262144/256,256, 0, stream>>>((const float*)d_in[21], WT + O_WF2,  1024, 256, LSTRIDE);
    bias_pack_kernel<<<9, 256, 0, stream>>>((const float*)d_in[10], (const float*)d_in[12], PB);

    concat_init_kernel<<<2*5440, 256, 0, stream>>>(srcs[0], srcs[1], srcs[2], srcs[3],
                                                   poss[0], poss[1], poss[2], poss[3],
                                                   le, X, POSB, XB, QB);

    for (int l = 0; l < L_; l++) {
        const ushort_t* wt = WT + (size_t)l * LSTRIDE;
        const float* bval = (const float*)d_in[14] + (size_t)l * C_;
        const float* bout = (const float*)d_in[16] + (size_t)l * C_;
        const float* g1   = (const float*)d_in[17] + (size_t)l * C_;
        const float* b1   = (const float*)d_in[18] + (size_t)l * C_;
        const float* bf1  = (const float*)d_in[20] + (size_t)l * F_;
        const float* bf2  = (const float*)d_in[22] + (size_t)l * C_;
        const float* g2   = (const float*)d_in[23] + (size_t)l * C_;
        const float* b2   = (const float*)d_in[24] + (size_t)l * C_;

        gemm_bf16_kernel<<<dim3(2, M_/128), 256, 0, stream>>>(XB, wt + O_WVAL, bval,
            VALB, nullptr, nullptr, M_, 256, 256, 256, 0);
        // fused offset+attn projection: N=384 (cols 0:256 -> OFFf, 256:384 -> ATTf)
        gemm_bf16_kernel<<<dim3(3, M_/128), 256, 0, stream>>>(QB, wt + O_WOFF, PB + (size_t)l*384,
            nullptr, OFFf, ATTf, M_, 384, 256, 256, 0);
        msdeform_kernel<<<M_/4, 128, 0, stream>>>(VALB, OFFf, ATTf, SAMPB);
        // out-proj fused with ln1: x = LN(x + attn_out)
        gemm_ln_kernel<<<M_/64, 256, 0, stream>>>(SAMPB, wt + O_WOUT, bout, 256,
            X, XB, g1, b1, nullptr, nullptr);
        gemm_bf16_kernel<<<dim3(8, M_/128), 256, 0, stream>>>(XB, wt + O_WF1, bf1,
            HB, nullptr, nullptr, M_, 1024, 256, 1024, 1);
        // ff2 fused with ln2: x = LN(x + ffn_out); also emits QB for next layer
        gemm_ln_kernel<<<M_/64, 256, 0, stream>>>(HB, wt + O_WF2, bf2, 1024,
            X, XB, g2, b2, POSB, QB);
    }
}

// Round 3
// 1901.681 us; speedup vs baseline: 1.0828x; 1.0828x over previous
//
#include <hip/hip_runtime.h>
#include <cstdint>
#include <cstddef>

#define B_  2
#define C_  256
#define NH_ 8
#define LV_ 4
#define P_  4
#define L_  6
#define F_  1024
#define N_  21760
#define M_  (B_*N_)   // 43520

typedef unsigned short ushort_t;
typedef __attribute__((ext_vector_type(8))) short bf16x8;
typedef __attribute__((ext_vector_type(4))) float f32x4;
typedef __attribute__((ext_vector_type(2))) float f32x2;

__device__ __forceinline__ float b2f(ushort_t u){
    union { unsigned int i; float f; } v; v.i = ((unsigned int)u) << 16; return v.f;
}
__device__ __forceinline__ ushort_t f2b(float f){
    union { float f; unsigned int i; } v; v.f = f;
    return (ushort_t)((v.i + 0x7fffu + ((v.i >> 16) & 1u)) >> 16);
}

// async global->LDS, 16B per lane, dst = wave-uniform base + lane*16
__device__ __forceinline__ void gload16(const void* g, void* l){
    __builtin_amdgcn_global_load_lds(
        (const __attribute__((address_space(1))) unsigned int*)g,
        (__attribute__((address_space(3))) unsigned int*)l, 16, 0, 0);
}

// ---------------------------------------------------------------------------
// Coalesced concat+transpose init. Block = one 32x32 tile of one (b,level).
// ---------------------------------------------------------------------------
__global__ __launch_bounds__(256) void concat_init_kernel(
    const float* __restrict__ s0, const float* __restrict__ s1,
    const float* __restrict__ s2, const float* __restrict__ s3,
    const float* __restrict__ p0, const float* __restrict__ p1,
    const float* __restrict__ p2, const float* __restrict__ p3,
    const float* __restrict__ le, float* __restrict__ X,
    ushort_t* __restrict__ POSB, ushort_t* __restrict__ XB,
    ushort_t* __restrict__ QB)
{
    int bid = blockIdx.x;
    int b = bid / 5440;
    int r = bid - b * 5440;
    const float* sp; const float* pp; int li, st, hw, t;
    if      (r < 4096){ li=0; st=0;     hw=16384; t=r;        sp=s0; pp=p0; }
    else if (r < 5120){ li=1; st=16384; hw=4096;  t=r-4096;   sp=s1; pp=p1; }
    else if (r < 5376){ li=2; st=20480; hw=1024;  t=r-5120;   sp=s2; pp=p2; }
    else              { li=3; st=21504; hw=256;   t=r-5376;   sp=s3; pp=p3; }
    int pt = t >> 3, ct = t & 7;   // pix-tile, c-tile (C/32 = 8)

    __shared__ float ts[32][33], tp[32][33];
    int tx  = threadIdx.x & 31;
    int ty8 = threadIdx.x >> 5;    // 0..7
#pragma unroll
    for (int i = 0; i < 4; i++) {
        int c   = ct * 32 + ty8 + i * 8;
        int pix = pt * 32 + tx;
        size_t so = ((size_t)b * C_ + c) * hw + pix;
        ts[ty8 + i * 8][tx] = sp[so];
        tp[ty8 + i * 8][tx] = pp[so];
    }
    __syncthreads();
#pragma unroll
    for (int i = 0; i < 4; i++) {
        int cw = tx, pw = ty8 + i * 8;
        int c = ct * 32 + cw;
        int n = st + pt * 32 + pw;
        size_t o = ((size_t)b * N_ + n) * C_ + c;
        float xv = ts[cw][pw];
        float pv = tp[cw][pw] + le[li * C_ + c];
        X[o]    = xv;
        XB[o]   = f2b(xv);
        POSB[o] = f2b(pv);
        QB[o]   = f2b(xv + pv);
    }
}

// ---------------------------------------------------------------------------
// Weight prep: fp32 [L][K][N] -> bf16 [l*outStride + n*K + k]  (transpose+cast)
// ---------------------------------------------------------------------------
__global__ __launch_bounds__(256) void wprep_kernel(
    const float* __restrict__ in, ushort_t* __restrict__ out,
    int K, int Nn, long outLayerStride)
{
    int idx = blockIdx.x * 256 + threadIdx.x;     // < L*K*N
    int per = K * Nn;
    int l   = idx / per;
    int rem = idx - l * per;
    int k   = rem / Nn;
    int nn  = rem - k * Nn;
    out[(long)l * outLayerStride + (long)nn * K + k] = f2b(in[idx]);
}

// packed bias for fused off+att GEMM: pb[l][0:256]=boff, [256:384]=batt
__global__ __launch_bounds__(256) void bias_pack_kernel(
    const float* __restrict__ boff, const float* __restrict__ batt,
    float* __restrict__ pb)
{
    int i = blockIdx.x * 256 + threadIdx.x;       // < 6*384
    if (i >= 6 * 384) return;
    int l = i / 384, j = i - l * 384;
    pb[i] = (j < 256) ? boff[l * 256 + j] : batt[l * 128 + j - 256];
}

// ---------------------------------------------------------------------------
// bf16 MFMA GEMM: C[M,N] = A[M,K](bf16) @ BT[N,K](bf16)^T + bias (fp32)
// 128x128 tile, 256 thr = 4 waves (2x2 of 64x64), 16x16x32 MFMA.
// Software-pipelined (T3/T4 minimum 2-phase): double-buffered BK=32 tiles,
// STAGE(next) issued before COMPUTE(cur); counted s_waitcnt vmcnt(4) leaves
// the prefetch in flight across raw s_barrier (no __syncthreads drain).
// LDS 32KB -> 5 blocks/CU capacity (unchanged from unpipelined version).
// ---------------------------------------------------------------------------
__global__ __launch_bounds__(256) void gemm_bf16_kernel(
    const ushort_t* __restrict__ A, const ushort_t* __restrict__ BT,
    const float* __restrict__ bias,
    ushort_t* __restrict__ Cb, float* __restrict__ Cf, float* __restrict__ Cf2,
    int M, int Nn, int K, int Nsplit, int relu)
{
    __shared__ ushort_t Alds[2][128*32];
    __shared__ ushort_t Blds[2][128*32];
    const int tid  = threadIdx.x;
    const int wave = tid >> 6, lane = tid & 63;
    const int bm = blockIdx.y * 128, bn = blockIdx.x * 128;
    const int wm = (wave >> 1) * 64, wn = (wave & 1) * 64;

    // staging: unit = 16 rows x 32 cols (1KB). Wave stages 2 units of A + 2 of B.
    const int c0 = wave * 2, c1 = wave * 2 + 1;
    const int rIn = lane >> 2;
    const int cIn = (lane & 3) * 8;
    const ushort_t* Ag0 = A  + (size_t)(bm + c0*16 + rIn) * K + cIn;
    const ushort_t* Ag1 = A  + (size_t)(bm + c1*16 + rIn) * K + cIn;
    const ushort_t* Bg0 = BT + (size_t)(bn + c0*16 + rIn) * K + cIn;
    const ushort_t* Bg1 = BT + (size_t)(bn + c1*16 + rIn) * K + cIn;

    const int fm    = lane & 15;
    const int quad8 = (lane >> 4) * 8;

    f32x4 acc[4][4];
#pragma unroll
    for (int i = 0; i < 4; i++)
#pragma unroll
        for (int j = 0; j < 4; j++) acc[i][j] = (f32x4){0.f,0.f,0.f,0.f};

    auto stageBuf = [&](int bufi, int kk) {
        gload16(Ag0 + kk, &Alds[bufi][c0*512]);
        gload16(Ag1 + kk, &Alds[bufi][c1*512]);
        gload16(Bg0 + kk, &Blds[bufi][c0*512]);
        gload16(Bg1 + kk, &Blds[bufi][c1*512]);
    };
    auto computeBuf = [&](int bufi) {
        bf16x8 af[4], bfr[4];
#pragma unroll
        for (int i = 0; i < 4; i++)
            af[i]  = *(const bf16x8*)&Alds[bufi][(wm + i*16 + fm) * 32 + quad8];
#pragma unroll
        for (int j = 0; j < 4; j++)
            bfr[j] = *(const bf16x8*)&Blds[bufi][(wn + j*16 + fm) * 32 + quad8];
#pragma unroll
        for (int i = 0; i < 4; i++)
#pragma unroll
            for (int j = 0; j < 4; j++)
                acc[i][j] = __builtin_amdgcn_mfma_f32_16x16x32_bf16(af[i], bfr[j], acc[i][j], 0, 0, 0);
    };

    // WAITBAR: my previous tile's 4 loads done (4 newest stay in flight),
    // then block-wide barrier => all waves' previous-tile loads complete.
#define WAITBAR4() do { \
        asm volatile("s_waitcnt vmcnt(4)" ::: "memory"); \
        __builtin_amdgcn_sched_barrier(0); \
        __builtin_amdgcn_s_barrier(); } while (0)
    // FENCEBAR: all waves finished reading the buffer (WAR guard before restage)
#define FENCEBAR() do { \
        asm volatile("" ::: "memory"); \
        __builtin_amdgcn_s_barrier(); } while (0)

    const int nk = K >> 5;             // K/32 tiles; always even here (8 or 32)
    stageBuf(0, 0);
    int k = 32;
    for (int t = 0; t + 2 < nk; t += 2) {
        stageBuf(1, k); k += 32;       // prefetch tile t+1
        WAITBAR4();
        computeBuf(0);                 // tile t
        FENCEBAR();
        stageBuf(0, k); k += 32;       // prefetch tile t+2
        WAITBAR4();
        computeBuf(1);                 // tile t+1
        FENCEBAR();
    }
    stageBuf(1, k);                    // last tile (nk-1)
    WAITBAR4();
    computeBuf(0);                     // tile nk-2
    asm volatile("s_waitcnt vmcnt(0)" ::: "memory");
    __builtin_amdgcn_sched_barrier(0);
    __builtin_amdgcn_s_barrier();
    computeBuf(1);                     // tile nk-1
#undef WAITBAR4
#undef FENCEBAR

    const int rq = (lane >> 4) * 4;
#pragma unroll
    for (int j = 0; j < 4; j++) {
        int col = bn + wn + j*16 + fm;
        float bb = bias[col];
#pragma unroll
        for (int i = 0; i < 4; i++) {
            int row0 = bm + wm + i*16 + rq;
#pragma unroll
            for (int r = 0; r < 4; r++) {
                float v = acc[i][j][r] + bb;
                if (relu) v = fmaxf(v, 0.f);
                if (Cb) {
                    Cb[(size_t)(row0 + r) * Nn + col] = f2b(v);
                } else if (col < Nsplit) {
                    Cf[(size_t)(row0 + r) * Nsplit + col] = v;
                } else {
                    Cf2[(size_t)(row0 + r) * (Nn - Nsplit) + (col - Nsplit)] = v;
                }
            }
        }
    }
}

// ---------------------------------------------------------------------------
// x = LN(x + res_bf16)*g + b; writes X fp32, Xb bf16, optional Qb=bf16(x+posb)
// ---------------------------------------------------------------------------
__global__ __launch_bounds__(256) void ln_residual_kernel(
    float* __restrict__ x, const ushort_t* __restrict__ res,
    const float* __restrict__ g, const float* __restrict__ bta,
    ushort_t* __restrict__ xb, const ushort_t* __restrict__ posb,
    ushort_t* __restrict__ qb)
{
    int row  = blockIdx.x * 4 + (threadIdx.x >> 6);
    int lane = threadIdx.x & 63;
    size_t base = (size_t)row * C_ + lane * 4;
    float4  xv = *(const float4*)(x + base);
    ushort4 rv = *(const ushort4*)(res + base);
    float v0 = xv.x + b2f(rv.x), v1 = xv.y + b2f(rv.y);
    float v2 = xv.z + b2f(rv.z), v3 = xv.w + b2f(rv.w);
    float s  = v0 + v1 + v2 + v3;
    float s2 = v0*v0 + v1*v1 + v2*v2 + v3*v3;
#pragma unroll
    for (int off = 1; off < 64; off <<= 1) {
        s  += __shfl_xor(s,  off, 64);
        s2 += __shfl_xor(s2, off, 64);
    }
    float mu  = s * (1.f / C_);
    float var = s2 * (1.f / C_) - mu * mu;
    float rs  = rsqrtf(var + 1e-5f);
    float4 gv = *(const float4*)(g + lane * 4);
    float4 bv = *(const float4*)(bta + lane * 4);
    float4 o;
    o.x = (v0 - mu) * rs * gv.x + bv.x;
    o.y = (v1 - mu) * rs * gv.y + bv.y;
    o.z = (v2 - mu) * rs * gv.z + bv.z;
    o.w = (v3 - mu) * rs * gv.w + bv.w;
    *(float4*)(x + base) = o;
    ushort4 ob; ob.x = f2b(o.x); ob.y = f2b(o.y); ob.z = f2b(o.z); ob.w = f2b(o.w);
    *(ushort4*)(xb + base) = ob;
    if (qb) {
        ushort4 pv = *(const ushort4*)(posb + base);
        ushort4 qv;
        qv.x = f2b(o.x + b2f(pv.x)); qv.y = f2b(o.y + b2f(pv.y));
        qv.z = f2b(o.z + b2f(pv.z)); qv.w = f2b(o.w + b2f(pv.w));
        *(ushort4*)(qb + base) = qv;
    }
}

// ---------------------------------------------------------------------------
// Deformable sampling, 2-phase. Block = 128 thr per FOUR queries.
// ---------------------------------------------------------------------------
__global__ __launch_bounds__(128) void msdeform_kernel(
    const ushort_t* __restrict__ VALb, const float* __restrict__ OFF,
    const float* __restrict__ ATT, ushort_t* __restrict__ SAMPb)
{
    const int bq0 = blockIdx.x << 2;          // first of 4 query indices
    const int b   = bq0 / N_;                 // block-uniform (N_ % 4 == 0)
    const int tid = threadIdx.x;

    __shared__ int2 s_wi[32 * 65];            // [G = qi*8+head][64 +1 pad]

    {   // phase 1 — head = tid>>4, li = (tid>>2)&3, p = tid&3
        const int head = tid >> 4, li = (tid >> 2) & 3;
        const int HS[4] = {128, 64, 32, 16};
        const int ST[4] = {0, 16384, 20480, 21504};
        const int wl = HS[li], stl = ST[li];
        const float fw = (float)wl;

#pragma unroll
        for (int qi = 0; qi < 4; qi++) {
            const int bn = bq0 + qi;
            const int n  = bn - b * N_;
            float logit = ATT[(size_t)bn * 128 + tid];
            float2 o2 = *(const float2*)(OFF + (size_t)bn * 256 + tid * 2);
            float ox = o2.x, oy = o2.y;
            float mx = logit;
#pragma unroll
            for (int s = 1; s < 16; s <<= 1) mx = fmaxf(mx, __shfl_xor(mx, s, 16));
            float e = __expf(logit - mx), sm = e;
#pragma unroll
            for (int s = 1; s < 16; s <<= 1) sm += __shfl_xor(sm, s, 16);
            float aw = e / sm;

            int sq, lwq;
            if      (n < 16384){ sq = 0;     lwq = 7; }
            else if (n < 20480){ sq = 16384; lwq = 6; }
            else if (n < 21504){ sq = 20480; lwq = 5; }
            else               { sq = 21504; lwq = 4; }
            int pidx = n - sq;
            int prow = pidx >> lwq, pcol = pidx & ((1 << lwq) - 1);
            float inv = 1.f / (float)(1 << lwq);
            float refx = (pcol + 0.5f) * inv;
            float refy = (prow + 0.5f) * inv;

            float xx = refx * fw + ox - 0.5f;   // (refx + ox/w)*w - 0.5
            float yy = refy * fw + oy - 0.5f;
            float xf = floorf(xx), yf = floorf(yy);
            float wx = xx - xf, wy = yy - yf;
            int x0 = (int)xf, y0 = (int)yf;
            const int base = (qi * 8 + head) * 65 + (tid & 15) * 4;
#pragma unroll
            for (int c2 = 0; c2 < 4; c2++) {
                int dx = c2 & 1, dy = c2 >> 1;
                int xi = x0 + dx, yi = y0 + dy;
                float wgt = (dx ? wx : 1.f - wx) * (dy ? wy : 1.f - wy);
                bool valid = (xi >= 0) & (xi < wl) & (yi >= 0) & (yi < wl);
                int xc = min(max(xi, 0), wl - 1), yc = min(max(yi, 0), wl - 1);
                int2 wi;
                wi.x = ((stl + yc * wl + xc) * C_ + head * 32) * 2;  // byte off
                wi.y = __float_as_int(valid ? aw * wgt : 0.f);
                s_wi[base + c2] = wi;
            }
        }
    }
    __syncthreads();

    // phase 2 — q2 = tid>>5, head = (tid>>2)&7, 16B chunk = tid&3
    const int q2     = tid >> 5;
    const int within = tid & 31;
    const int head   = within >> 2;
    const int ch16   = (within & 3) << 4;     // byte offset inside head's 64B
    const int bn     = bq0 + q2;
    const char* vb   = (const char*)(VALb + (size_t)b * (N_ * C_)); // SGPR base
    const int sbase  = (q2 * 8 + head) * 65;

    f32x2 a0 = {0.f,0.f}, a1 = {0.f,0.f}, a2 = {0.f,0.f}, a3 = {0.f,0.f};
#pragma unroll 8
    for (int j = 0; j < 64; j++) {
        int2 wi = s_wi[sbase + j];
        float w = __int_as_float(wi.y);
        f32x2 w2 = {w, w};
        uint4 u = *(const uint4*)(vb + (unsigned)(wi.x + ch16));
        f32x2 f;
        f.x = __uint_as_float(u.x << 16);
        f.y = __uint_as_float(u.x & 0xffff0000u);
        a0 += w2 * f;
        f.x = __uint_as_float(u.y << 16);
        f.y = __uint_as_float(u.y & 0xffff0000u);
        a1 += w2 * f;
        f.x = __uint_as_float(u.z << 16);
        f.y = __uint_as_float(u.z & 0xffff0000u);
        a2 += w2 * f;
        f.x = __uint_as_float(u.w << 16);
        f.y = __uint_as_float(u.w & 0xffff0000u);
        a3 += w2 * f;
    }
    uint4 o;
    o.x = (unsigned)f2b(a0.x) | ((unsigned)f2b(a0.y) << 16);
    o.y = (unsigned)f2b(a1.x) | ((unsigned)f2b(a1.y) << 16);
    o.z = (unsigned)f2b(a2.x) | ((unsigned)f2b(a2.y) << 16);
    o.w = (unsigned)f2b(a3.x) | ((unsigned)f2b(a3.y) << 16);
    *(uint4*)(SAMPb + (size_t)bn * C_ + head * 32 + ((within & 3) << 3)) = o;
}

// ---------------------------------------------------------------------------
// Workspace (bytes), ~185.3 MB:
//   POSB bf16 22.28M | OFFf f32 44.56M | ATTf f32 22.28M | SAMPB bf16 22.28M |
//   VALB bf16 22.28M | XB 22.28M | QB 22.28M | WT bf16 9.04M | PB 9216B
//   FFN hidden HB (bf16, M*1024) overlays [OFFf|ATTf|SAMPB] exactly.
//   VALB also hosts attn-out and FFN-out (dead-time reuse).
// ---------------------------------------------------------------------------
extern "C" void kernel_launch(void* const* d_in, const int* in_sizes, int n_in,
                              void* d_out, int out_size, void* d_ws, size_t ws_size,
                              hipStream_t stream)
{
    const float *srcs[4], *poss[4];
    if (in_sizes[1] == in_sizes[0]) {   // interleaved src0,pos0,src1,pos1,...
        srcs[0] = (const float*)d_in[0]; poss[0] = (const float*)d_in[1];
        srcs[1] = (const float*)d_in[2]; poss[1] = (const float*)d_in[3];
        srcs[2] = (const float*)d_in[4]; poss[2] = (const float*)d_in[5];
        srcs[3] = (const float*)d_in[6]; poss[3] = (const float*)d_in[7];
    } else {
        srcs[0] = (const float*)d_in[0]; srcs[1] = (const float*)d_in[1];
        srcs[2] = (const float*)d_in[2]; srcs[3] = (const float*)d_in[3];
        poss[0] = (const float*)d_in[4]; poss[1] = (const float*)d_in[5];
        poss[2] = (const float*)d_in[6]; poss[3] = (const float*)d_in[7];
    }
    const float* le = (const float*)d_in[8];

    float* X = (float*)d_out;
    char* w = (char*)d_ws;
    ushort_t* POSB  = (ushort_t*)w;           w += (size_t)M_ * C_ * 2;
    float*    OFFf  = (float*)w;              w += (size_t)M_ * C_ * 4;
    float*    ATTf  = (float*)w;              w += (size_t)M_ * 128 * 4;
    ushort_t* SAMPB = (ushort_t*)w;           w += (size_t)M_ * C_ * 2;
    ushort_t* VALB  = (ushort_t*)w;           w += (size_t)M_ * C_ * 2;
    ushort_t* XB    = (ushort_t*)w;           w += (size_t)M_ * C_ * 2;
    ushort_t* QB    = (ushort_t*)w;           w += (size_t)M_ * C_ * 2;
    ushort_t* WT    = (ushort_t*)w;           w += (size_t)6 * 753664 * 2;
    float*    PB    = (float*)w;
    ushort_t* HB    = (ushort_t*)OFFf;        // overlays OFFf|ATTf|SAMPB exactly

    // per-layer WT element offsets ([val][off|att packed][out][ff1][ff2])
    const long LSTRIDE = 753664;
    const long O_WVAL = 0, O_WOFF = 65536, O_WATT = 131072, O_WOUT = 163840,
               O_WF1 = 229376, O_WF2 = 491520;

    wprep_kernel<<<6*65536/256, 256, 0, stream>>>((const float*)d_in[13], WT + O_WVAL, 256, 256,  LSTRIDE);
    wprep_kernel<<<6*65536/256, 256, 0, stream>>>((const float*)d_in[9],  WT + O_WOFF, 256, 256,  LSTRIDE);
    wprep_kernel<<<6*32768/256, 256, 0, stream>>>((const float*)d_in[11], WT + O_WATT, 256, 128,  LSTRIDE);
    wprep_kernel<<<6*65536/256, 256, 0, stream>>>((const float*)d_in[15], WT + O_WOUT, 256, 256,  LSTRIDE);
    wprep_kernel<<<6*262144/256,256, 0, stream>>>((const float*)d_in[19], WT + O_WF1,  256, 1024, LSTRIDE);
    wprep_kernel<<<6*262144/256,256, 0, stream>>>((const float*)d_in[21], WT + O_WF2,  1024, 256, LSTRIDE);
    bias_pack_kernel<<<9, 256, 0, stream>>>((const float*)d_in[10], (const float*)d_in[12], PB);

    concat_init_kernel<<<2*5440, 256, 0, stream>>>(srcs[0], srcs[1], srcs[2], srcs[3],
                                                   poss[0], poss[1], poss[2], poss[3],
                                                   le, X, POSB, XB, QB);

    for (int l = 0; l < L_; l++) {
        const ushort_t* wt = WT + (size_t)l * LSTRIDE;
        const float* bval = (const float*)d_in[14] + (size_t)l * C_;
        const float* bout = (const float*)d_in[16] + (size_t)l * C_;
        const float* g1   = (const float*)d_in[17] + (size_t)l * C_;
        const float* b1   = (const float*)d_in[18] + (size_t)l * C_;
        const float* bf1  = (const float*)d_in[20] + (size_t)l * F_;
        const float* bf2  = (const float*)d_in[22] + (size_t)l * C_;
        const float* g2   = (const float*)d_in[23] + (size_t)l * C_;
        const float* b2   = (const float*)d_in[24] + (size_t)l * C_;

        gemm_bf16_kernel<<<dim3(2, M_/128), 256, 0, stream>>>(XB, wt + O_WVAL, bval,
            VALB, nullptr, nullptr, M_, 256, 256, 256, 0);
        // fused offset+attn projection: N=384 (cols 0:256 -> OFFf, 256:384 -> ATTf)
        gemm_bf16_kernel<<<dim3(3, M_/128), 256, 0, stream>>>(QB, wt + O_WOFF, PB + (size_t)l*384,
            nullptr, OFFf, ATTf, M_, 384, 256, 256, 0);
        msdeform_kernel<<<M_/4, 128, 0, stream>>>(VALB, OFFf, ATTf, SAMPB);
        gemm_bf16_kernel<<<dim3(2, M_/128), 256, 0, stream>>>(SAMPB, wt + O_WOUT, bout,
            VALB, nullptr, nullptr, M_, 256, 256, 256, 0);
        ln_residual_kernel<<<M_/4, 256, 0, stream>>>(X, VALB, g1, b1, XB, nullptr, nullptr);
        gemm_bf16_kernel<<<dim3(8, M_/128), 256, 0, stream>>>(XB, wt + O_WF1, bf1,
            HB, nullptr, nullptr, M_, 1024, 256, 1024, 1);
        gemm_bf16_kernel<<<dim3(2, M_/128), 256, 0, stream>>>(HB, wt + O_WF2, bf2,
            VALB, nullptr, nullptr, M_, 256, 1024, 256, 0);
        ln_residual_kernel<<<M_/4, 256, 0, stream>>>(X, VALB, g2, b2, XB, POSB, QB);
    }
}